// Round 1
// baseline (83.278 us; speedup 1.0000x reference)
//
#include <hip/hip_runtime.h>
#include <stdint.h>

#define N 2048
#define F 128
#define ALPHA 1.0f

typedef __bf16 bf16x8 __attribute__((ext_vector_type(8)));
typedef float f32x4 __attribute__((ext_vector_type(4)));

// ws layout:
//   [0, 512K)          : Xb  - bf16 copy of X (2048*128)
//   [512K, 512K+8K)    : n[2048]  - row squared norms (of bf16-rounded X)
//   [520K+?  .. ]      : s[128]   - column sums, then nsum scalar
static constexpr size_t WS_XB   = 0;
static constexpr size_t WS_N    = (size_t)N * F * 2;        // 524288
static constexpr size_t WS_S    = WS_N + (size_t)N * 4;     // 532480
static constexpr size_t WS_NSUM = WS_S + F * 4;             // 532992

// ---------------- prep: fp32 -> bf16, row norms, column sums ----------------
__global__ __launch_bounds__(1024) void gk_prep(const float* __restrict__ X,
                                                ushort* __restrict__ Xb,
                                                float* __restrict__ nrm,
                                                float* __restrict__ s,
                                                float* __restrict__ nsum) {
    __shared__ float s_lds[F];
    __shared__ float n_lds[64];
    const int t = threadIdx.x;
    if (t < F) s_lds[t] = 0.f;
    if (t < 64) n_lds[t] = 0.f;
    __syncthreads();

    const int rowBase = blockIdx.x * 64;           // 64 rows per block
    const int r  = t >> 4;                         // row within block (16 thr/row)
    const int k0 = (t & 15) * 8;                   // 8 floats per thread

    const float4* px = reinterpret_cast<const float4*>(X + (size_t)(rowBase + r) * F + k0);
    float4 v0 = px[0], v1 = px[1];
    float xv[8] = {v0.x, v0.y, v0.z, v0.w, v1.x, v1.y, v1.z, v1.w};

    uint32_t us[8];
    float xb[8];
    float ns = 0.f;
#pragma unroll
    for (int j = 0; j < 8; ++j) {
        uint32_t u = __float_as_uint(xv[j]);
        u = (u + 0x7FFFu + ((u >> 16) & 1u)) >> 16;   // RNE truncate to bf16
        us[j] = u;
        float fb = __uint_as_float(u << 16);
        xb[j] = fb;
        ns += fb * fb;
    }
    uint4 packed;
    packed.x = us[0] | (us[1] << 16);
    packed.y = us[2] | (us[3] << 16);
    packed.z = us[4] | (us[5] << 16);
    packed.w = us[6] | (us[7] << 16);
    *reinterpret_cast<uint4*>(Xb + (size_t)(rowBase + r) * F + k0) = packed;

    atomicAdd(&n_lds[r], ns);
#pragma unroll
    for (int j = 0; j < 8; ++j) atomicAdd(&s_lds[k0 + j], xb[j]);
    __syncthreads();

    if (t < 64) {                                  // wave 0: finalize row norms + nsum
        float v = n_lds[t];
        nrm[rowBase + t] = v;
#pragma unroll
        for (int off = 32; off; off >>= 1) v += __shfl_xor(v, off, 64);
        if (t == 0) atomicAdd(nsum, v);
    }
    if (t >= 256 && t < 256 + F) {                 // wave 4-5: flush column sums
        atomicAdd(&s[t - 256], s_lds[t - 256]);
    }
}

// ---------------- main: C = exp(-(n_i + n_j - 2 X X^T) / (2 sigma^2)) -------
// block = 256 threads (4 waves); block tile 128 rows x 64 cols; wave tile 32x64.
__global__ __launch_bounds__(256) void gk_main(const __bf16* __restrict__ Xb,
                                               const float* __restrict__ nrm,
                                               const float* __restrict__ s,
                                               const float* __restrict__ nsum,
                                               float* __restrict__ out) {
    __shared__ float sh_scale;
    const int t = threadIdx.x;

    if (t < 64) {                                  // per-block sigma computation
        float a0 = s[t * 2], a1 = s[t * 2 + 1];
        float v = a0 * a0 + a1 * a1;
#pragma unroll
        for (int off = 32; off; off >>= 1) v += __shfl_xor(v, off, 64);
        if (t == 0) {
            float sn = *nsum;
            float meand2 = 2.f * sn / (float)N - 2.f * v / ((float)N * (float)N);
            float sigma2 = ALPHA * meand2;
            sh_scale = -1.f / (2.f * sigma2);
        }
    }
    __syncthreads();
    const float scale = sh_scale;

    const int wave = t >> 6, lane = t & 63;
    const int quad = lane >> 4, l16 = lane & 15;

    const int row0 = blockIdx.y * 128 + wave * 32;
    const int col0 = blockIdx.x * 64;

    // A/B fragments straight from L2-resident bf16 X.
    // Verified layouts: A[m=lane&15][k=quad*8+j], B[k=quad*8+j][n=lane&15]
    // (B = X^T so b_frag loads identically to a_frag from row col0+...).
    bf16x8 afr[2][4], bfr[4][4];
#pragma unroll
    for (int mi = 0; mi < 2; ++mi)
#pragma unroll
        for (int kc = 0; kc < 4; ++kc)
            afr[mi][kc] = *reinterpret_cast<const bf16x8*>(
                Xb + (size_t)(row0 + mi * 16 + l16) * F + kc * 32 + quad * 8);
#pragma unroll
    for (int ni = 0; ni < 4; ++ni)
#pragma unroll
        for (int kc = 0; kc < 4; ++kc)
            bfr[ni][kc] = *reinterpret_cast<const bf16x8*>(
                Xb + (size_t)(col0 + ni * 16 + l16) * F + kc * 32 + quad * 8);

    float nr[2][4], nc[4];
#pragma unroll
    for (int mi = 0; mi < 2; ++mi)
#pragma unroll
        for (int rg = 0; rg < 4; ++rg)
            nr[mi][rg] = nrm[row0 + mi * 16 + quad * 4 + rg];
#pragma unroll
    for (int ni = 0; ni < 4; ++ni)
        nc[ni] = nrm[col0 + ni * 16 + l16];

#pragma unroll
    for (int mi = 0; mi < 2; ++mi) {
#pragma unroll
        for (int ni = 0; ni < 4; ++ni) {
            f32x4 acc = {0.f, 0.f, 0.f, 0.f};
#pragma unroll
            for (int kc = 0; kc < 4; ++kc)
                acc = __builtin_amdgcn_mfma_f32_16x16x32_bf16(afr[mi][kc], bfr[ni][kc], acc, 0, 0, 0);
            const int col = col0 + ni * 16 + l16;
#pragma unroll
            for (int rg = 0; rg < 4; ++rg) {
                const int row = row0 + mi * 16 + quad * 4 + rg;
                float d2 = fmaxf(nr[mi][rg] + nc[ni] - 2.f * acc[rg], 0.f);
                out[(size_t)row * N + col] = __expf(scale * d2);
            }
        }
    }
}

extern "C" void kernel_launch(void* const* d_in, const int* in_sizes, int n_in,
                              void* d_out, int out_size, void* d_ws, size_t ws_size,
                              hipStream_t stream) {
    const float* X = (const float*)d_in[0];
    float* out = (float*)d_out;
    char* ws = (char*)d_ws;

    ushort* Xb   = (ushort*)(ws + WS_XB);
    float*  nrm  = (float*)(ws + WS_N);
    float*  s    = (float*)(ws + WS_S);
    float*  nsum = (float*)(ws + WS_NSUM);

    // zero the atomic accumulators (s[128] + nsum)
    hipMemsetAsync(ws + WS_S, 0, (F + 1) * sizeof(float), stream);

    gk_prep<<<N / 64, 1024, 0, stream>>>(X, Xb, nrm, s, nsum);

    dim3 grid(N / 64, N / 128);   // x: col tiles (64), y: row tiles (128)
    gk_main<<<grid, 256, 0, stream>>>((const __bf16*)Xb, nrm, s, nsum, out);
}

// Round 2
// 67.027 us; speedup vs baseline: 1.2424x; 1.2424x over previous
//
#include <hip/hip_runtime.h>
#include <stdint.h>

#define N 2048
#define F 128
#define ALPHA 1.0f
#define PREP_BLOCKS 32

typedef __bf16 bf16x8 __attribute__((ext_vector_type(8)));
typedef float f32x4 __attribute__((ext_vector_type(4)));

// ws layout:
//   [0, 512K)    : Xs        - bf16 X in fragment-major swizzled layout
//                  element (row, k) -> Xs[(row>>4)*2048 + (k>>3)*128 + (row&15)*8 + (k&7)]
//   then         : nrm[2048]       - row squared norms (of bf16-rounded X)
//   then         : s_part[32][128] - per-prep-block column sums
//   then         : nsum_part[32]   - per-prep-block sum of row norms
static constexpr size_t WS_XS    = 0;
static constexpr size_t WS_N     = (size_t)N * F * 2;            // 524288
static constexpr size_t WS_SP    = WS_N + (size_t)N * 4;         // +8192
static constexpr size_t WS_NSUMP = WS_SP + PREP_BLOCKS * F * 4;  // +16384

// ---------------- prep: fp32 -> bf16 (swizzled), row norms, column partials --
__global__ __launch_bounds__(1024) void gk_prep(const float* __restrict__ X,
                                                ushort* __restrict__ Xs,
                                                float* __restrict__ nrm,
                                                float* __restrict__ s_part,
                                                float* __restrict__ nsum_part) {
    __shared__ float s_lds[F];
    __shared__ float nw_lds[16];
    const int t = threadIdx.x;
    if (t < F) s_lds[t] = 0.f;
    __syncthreads();

    const int rowBase = blockIdx.x * 64;           // 64 rows per block
    const int r    = t >> 4;                       // row within block (16 thr/row)
    const int kidx = t & 15;                       // which 8-col chunk
    const int k0   = kidx * 8;
    const int row  = rowBase + r;

    const float4* px = reinterpret_cast<const float4*>(X + (size_t)row * F + k0);
    float4 v0 = px[0], v1 = px[1];
    float xv[8] = {v0.x, v0.y, v0.z, v0.w, v1.x, v1.y, v1.z, v1.w};

    uint32_t us[8];
    float xb[8];
    float ns = 0.f;
#pragma unroll
    for (int j = 0; j < 8; ++j) {
        uint32_t u = __float_as_uint(xv[j]);
        u = (u + 0x7FFFu + ((u >> 16) & 1u)) >> 16;   // RNE truncate to bf16
        us[j] = u;
        float fb = __uint_as_float(u << 16);
        xb[j] = fb;
        ns += fb * fb;
    }
    uint4 packed;
    packed.x = us[0] | (us[1] << 16);
    packed.y = us[2] | (us[3] << 16);
    packed.z = us[4] | (us[5] << 16);
    packed.w = us[6] | (us[7] << 16);
    // swizzled store: g = row>>4, c = kidx, l16 = row&15
    *reinterpret_cast<uint4*>(Xs + (size_t)(row >> 4) * 2048 + kidx * 128 + (row & 15) * 8) = packed;

    // row norm: butterfly over the 16 lanes sharing this row (lanes differ in kidx = low 4 bits)
    float nsr = ns;
#pragma unroll
    for (int off = 1; off < 16; off <<= 1) nsr += __shfl_xor(nsr, off, 64);
    if (kidx == 0) nrm[row] = nsr;
    // continue to full-wave sum (4 rows per wave), wave lane 0 stashes it
#pragma unroll
    for (int off = 16; off < 64; off <<= 1) nsr += __shfl_xor(nsr, off, 64);
    if ((t & 63) == 0) nw_lds[t >> 6] = nsr;

    // column partials: reduce the 4 rows within this wave (lanes differ by 16,32)
#pragma unroll
    for (int j = 0; j < 8; ++j) {
        float cj = xb[j];
        cj += __shfl_xor(cj, 16, 64);
        cj += __shfl_xor(cj, 32, 64);
        if ((t & 48) == 0) atomicAdd(&s_lds[k0 + j], cj);   // 16 waves -> 16-way
    }
    __syncthreads();

    if (t < F) s_part[blockIdx.x * F + t] = s_lds[t];
    if (t == 0) {
        float v = 0.f;
#pragma unroll
        for (int w = 0; w < 16; ++w) v += nw_lds[w];
        nsum_part[blockIdx.x] = v;
    }
}

// ---------------- main: C = exp(-(n_i + n_j - 2 X X^T) / (2 sigma^2)) -------
// block = 256 threads (4 waves); block tile 128 rows x 64 cols; wave tile 32x64.
__global__ __launch_bounds__(256) void gk_main(const __bf16* __restrict__ Xs,
                                               const float* __restrict__ nrm,
                                               const float* __restrict__ s_part,
                                               const float* __restrict__ nsum_part,
                                               float* __restrict__ out) {
    __shared__ float sh_scale;
    const int t = threadIdx.x;

    if (t < 64) {                                  // per-block sigma computation
        float sc0 = 0.f, sc1 = 0.f;
#pragma unroll
        for (int b = 0; b < PREP_BLOCKS; ++b) {
            sc0 += s_part[b * F + 2 * t];
            sc1 += s_part[b * F + 2 * t + 1];
        }
        float v = sc0 * sc0 + sc1 * sc1;
        float ns = (t < PREP_BLOCKS) ? nsum_part[t] : 0.f;
#pragma unroll
        for (int off = 32; off; off >>= 1) {
            v  += __shfl_xor(v, off, 64);
            ns += __shfl_xor(ns, off, 64);
        }
        if (t == 0) {
            float meand2 = 2.f * ns / (float)N - 2.f * v / ((float)N * (float)N);
            sh_scale = -1.f / (2.f * ALPHA * meand2);
        }
    }
    __syncthreads();
    const float scale = sh_scale;

    const int wave = t >> 6, lane = t & 63;
    const int quad = lane >> 4, l16 = lane & 15;

    const int row0 = blockIdx.y * 128 + wave * 32;
    const int col0 = blockIdx.x * 64;

    // Fragment loads from swizzled layout: one contiguous 1 KB per wave-load.
    // A[m=l16][k=(kc*4+quad)*8+j]  at Xs[(R0>>4)*2048 + (kc*4+quad)*128 + l16*8]
    bf16x8 afr[2][4], bfr[4][4];
#pragma unroll
    for (int mi = 0; mi < 2; ++mi) {
        const size_t gbase = (size_t)((row0 + mi * 16) >> 4) * 2048;
#pragma unroll
        for (int kc = 0; kc < 4; ++kc)
            afr[mi][kc] = *reinterpret_cast<const bf16x8*>(
                Xs + gbase + (kc * 4 + quad) * 128 + l16 * 8);
    }
#pragma unroll
    for (int ni = 0; ni < 4; ++ni) {
        const size_t gbase = (size_t)((col0 + ni * 16) >> 4) * 2048;
#pragma unroll
        for (int kc = 0; kc < 4; ++kc)
            bfr[ni][kc] = *reinterpret_cast<const bf16x8*>(
                Xs + gbase + (kc * 4 + quad) * 128 + l16 * 8);
    }

    float nr[2][4], nc[4];
#pragma unroll
    for (int mi = 0; mi < 2; ++mi)
#pragma unroll
        for (int rg = 0; rg < 4; ++rg)
            nr[mi][rg] = nrm[row0 + mi * 16 + quad * 4 + rg];
#pragma unroll
    for (int ni = 0; ni < 4; ++ni)
        nc[ni] = nrm[col0 + ni * 16 + l16];

#pragma unroll
    for (int mi = 0; mi < 2; ++mi) {
#pragma unroll
        for (int ni = 0; ni < 4; ++ni) {
            f32x4 acc = {0.f, 0.f, 0.f, 0.f};
#pragma unroll
            for (int kc = 0; kc < 4; ++kc)
                acc = __builtin_amdgcn_mfma_f32_16x16x32_bf16(afr[mi][kc], bfr[ni][kc], acc, 0, 0, 0);
            const int col = col0 + ni * 16 + l16;
#pragma unroll
            for (int rg = 0; rg < 4; ++rg) {
                const int row = row0 + mi * 16 + quad * 4 + rg;
                float d2 = fmaxf(nr[mi][rg] + nc[ni] - 2.f * acc[rg], 0.f);
                out[(size_t)row * N + col] = __expf(scale * d2);
            }
        }
    }
}

extern "C" void kernel_launch(void* const* d_in, const int* in_sizes, int n_in,
                              void* d_out, int out_size, void* d_ws, size_t ws_size,
                              hipStream_t stream) {
    const float* X = (const float*)d_in[0];
    float* out = (float*)d_out;
    char* ws = (char*)d_ws;

    ushort* Xs     = (ushort*)(ws + WS_XS);
    float*  nrm    = (float*)(ws + WS_N);
    float*  s_part = (float*)(ws + WS_SP);
    float*  nsum_p = (float*)(ws + WS_NSUMP);

    gk_prep<<<N / 64, 1024, 0, stream>>>(X, Xs, nrm, s_part, nsum_p);

    dim3 grid(N / 64, N / 128);   // x: col tiles (64), y: row tiles (128)
    gk_main<<<grid, 256, 0, stream>>>((const __bf16*)Xs, nrm, s_part, nsum_p, out);
}